// Round 1
// baseline (537.642 us; speedup 1.0000x reference)
//
#include <hip/hip_runtime.h>
#include <math.h>

// SIFA fused: depthwise-conv(+BN+ReLU) -> pixel-shuffle -> ch/sp gates -> s3 conv(+BN+SiLU)
// Key identity: stride-3 k=3 conv consumes exactly one 3x3 shuffle block:
//   z[b,o,oh,ow] = sum_{c,j} conv_w[o,c,j] * gate(y[b,c*9+j,oh,ow])
// so the 384x384 intermediate never materializes. Gate needs per-(b,c) mean/var
// over the 9*H*W values of channel c (computed by k_stats).

#define EPSF 1e-5f

static constexpr int B_ = 8, C_ = 64, H_ = 128, W_ = 128, OUP_ = 128;

// ws layout (float offsets)
static constexpr int WS_WFOLD = 0;       // 5184: wf[ce*9+k] = gen_w * gen_bn_scale
static constexpr int WS_SHIFT = 5184;    // 576 : gen bn shift per ce
static constexpr int WS_WT    = 5760;    // 73728: Wt[c][k][oup] = conv_w[oup][c][k]*bn_s[oup]
static constexpr int WS_BIAS  = 79488;   // 128 : conv bn bias
static constexpr int WS_GATE  = 79616;   // 512 * float4 {wa*cgate, 1-wa, a_sp, b_sp}

__device__ __forceinline__ float sigmf(float v) { return 1.f / (1.f + __expf(-v)); }

__global__ __launch_bounds__(256) void k_fold(
    const float* __restrict__ gen_w,
    const float* __restrict__ gg, const float* __restrict__ gb,
    const float* __restrict__ gm, const float* __restrict__ gv,
    const float* __restrict__ conv_w,
    const float* __restrict__ cg, const float* __restrict__ cb,
    const float* __restrict__ cm, const float* __restrict__ cv,
    float* __restrict__ ws)
{
    int idx = blockIdx.x * 256 + threadIdx.x;
    if (idx < 73728) {
        int c = idx / 1152; int r = idx - c * 1152; int k = r >> 7; int oup = r & 127;
        float s = cg[oup] * rsqrtf(cv[oup] + EPSF);
        ws[WS_WT + idx] = conv_w[(oup * C_ + c) * 9 + k] * s;
    } else if (idx < 73856) {
        int oup = idx - 73728;
        float s = cg[oup] * rsqrtf(cv[oup] + EPSF);
        ws[WS_BIAS + oup] = cb[oup] - cm[oup] * s;
    } else if (idx < 79040) {
        int i = idx - 73856; int ce = i / 9;
        float s = gg[ce] * rsqrtf(gv[ce] + EPSF);
        ws[WS_WFOLD + i] = gen_w[i] * s;
    } else if (idx < 79616) {
        int ce = idx - 79040;
        float s = gg[ce] * rsqrtf(gv[ce] + EPSF);
        ws[WS_SHIFT + ce] = gb[ce] - gm[ce] * s;
    }
}

// one block per (b,c): recompute depthwise conv, accumulate sum/sumsq over 9*H*W,
// emit the 4 gate constants.
__global__ __launch_bounds__(256) void k_stats(
    const float* __restrict__ x, const float* __restrict__ ws,
    const float* __restrict__ cwt, const float* __restrict__ cbs,
    const float* __restrict__ swt, const float* __restrict__ sbs,
    const float* __restrict__ gnw, const float* __restrict__ gnb,
    const float* __restrict__ wadd, float4* __restrict__ gate)
{
    int bid = blockIdx.x; int b = bid >> 6; int c = bid & 63;
    int t = threadIdx.x;
    const float* xp = x + (size_t)(b * C_ + c) * (H_ * W_);
    const float* wf = ws + WS_WFOLD + c * 81;   // block-uniform -> scalar loads
    const float* sh = ws + WS_SHIFT + c * 9;
    float s1 = 0.f, s2 = 0.f;
    for (int p = t; p < H_ * W_; p += 256) {
        int oh = p >> 7, ow = p & 127;
        float nb[9];
#pragma unroll
        for (int dy = 0; dy < 3; ++dy)
#pragma unroll
            for (int dx = 0; dx < 3; ++dx) {
                int yy = oh + dy - 1, xx = ow + dx - 1;
                float v = 0.f;
                if (yy >= 0 && yy < H_ && xx >= 0 && xx < W_) v = xp[yy * W_ + xx];
                nb[dy * 3 + dx] = v;
            }
#pragma unroll
        for (int j = 0; j < 9; ++j) {
            float v = sh[j];
#pragma unroll
            for (int k = 0; k < 9; ++k) v = fmaf(wf[j * 9 + k], nb[k], v);
            v = fmaxf(v, 0.f);
            s1 += v; s2 = fmaf(v, v, s2);
        }
    }
    __shared__ float r1[256], r2[256];
    r1[t] = s1; r2[t] = s2;
    __syncthreads();
    for (int s = 128; s > 0; s >>= 1) {
        if (t < s) { r1[t] += r1[t + s]; r2[t] += r2[t + s]; }
        __syncthreads();
    }
    if (t == 0) {
        const float N = 9.f * H_ * W_;
        float mean = r1[0] / N;
        float var = r2[0] / N - mean * mean;       // jnp.var ddof=0
        float invstd = rsqrtf(var + EPSF);
        int cgi = c & 7;                            // c = gidx*8 + cg
        float wa = wadd[0];
        float cgate = sigmf(cwt[cgi] * mean + cbs[cgi]);
        float4 o;
        o.x = wa * cgate;
        o.y = 1.f - wa;
        o.z = swt[cgi] * gnw[cgi] * invstd;
        o.w = swt[cgi] * (gnb[cgi] - mean * invstd * gnw[cgi]) + sbs[cgi];
        gate[bid] = o;
    }
}

// one block per (b, 8x8 output tile): all 128 oups.
// Per channel c: stage x halo + Wt chunk in LDS, compute gated u[9][64] in LDS,
// then register-blocked rank-9 update: thread owns 4 pixels x 8 oups.
__global__ __launch_bounds__(256) void k_main(
    const float* __restrict__ x, const float* __restrict__ ws,
    float* __restrict__ out)
{
    __shared__ float wf_s[5184];
    __shared__ float sh_s[576];
    __shared__ float bias_s[128];
    __shared__ float xs[120];     // 10 rows x stride 12
    __shared__ float W_s[1152];   // [k][oup]
    __shared__ float u_s[576];    // [j][64]

    int t = threadIdx.x;
    int bid = blockIdx.x;
    int b = bid >> 8; int tile = bid & 255;
    int oh0 = (tile >> 4) << 3, ow0 = (tile & 15) << 3;

    for (int i = t; i < 5184; i += 256) wf_s[i] = ws[WS_WFOLD + i];
    for (int i = t; i < 576; i += 256) sh_s[i] = ws[WS_SHIFT + i];
    if (t < 128) bias_s[t] = ws[WS_BIAS + t];

    const float4* gate = (const float4*)(ws + WS_GATE);
    const float* xb = x + (size_t)b * (C_ * H_ * W_);

    int lane = t & 63, wv = t >> 6;
    int my = lane >> 3, mx = lane & 7;          // phase-u pixel
    int m0 = (t & 15) << 2, n0 = (t >> 4) << 3; // matmul: 4 pixels, 8 oups

    float acc[4][8];
#pragma unroll
    for (int i = 0; i < 4; ++i)
#pragma unroll
        for (int j = 0; j < 8; ++j) acc[i][j] = 0.f;

    for (int c = 0; c < C_; ++c) {
        __syncthreads();
        if (t < 100) {  // 10x10 halo with zero pad
            int r = t / 10, cc = t - r * 10;
            int yy = oh0 + r - 1, xx = ow0 + cc - 1;
            float v = 0.f;
            if (yy >= 0 && yy < H_ && xx >= 0 && xx < W_) v = xb[c * (H_ * W_) + yy * W_ + xx];
            xs[r * 12 + cc] = v;
        }
        const float* Wt = ws + WS_WT + c * 1152;
#pragma unroll
        for (int i = 0; i < 5; ++i) {
            int ii = t + i * 256;
            if (ii < 1152) W_s[ii] = Wt[ii];
        }
        __syncthreads();

        // ---- phase u: wave wv handles j = wv, wv+4, (wv+8); lane = pixel
        float4 gt = gate[(b << 6) + c];
        float nb[9];
#pragma unroll
        for (int dy = 0; dy < 3; ++dy)
#pragma unroll
            for (int dx = 0; dx < 3; ++dx)
                nb[dy * 3 + dx] = xs[(my + dy) * 12 + (mx + dx)];
        for (int j = wv; j < 9; j += 4) {
            float v = sh_s[c * 9 + j];
#pragma unroll
            for (int k = 0; k < 9; ++k) v = fmaf(wf_s[(c * 9 + j) * 9 + k], nb[k], v);
            v = fmaxf(v, 0.f);
            float g2 = gt.x + gt.y * sigmf(fmaf(gt.z, v, gt.w));
            u_s[j * 64 + lane] = v * g2;
        }
        __syncthreads();

        // ---- rank-9 update: 27 float4 LDS reads + 288 FMA per thread
#pragma unroll
        for (int j = 0; j < 9; ++j) {
            const float4 um = *(const float4*)&u_s[j * 64 + m0];
            const float4 w0 = *(const float4*)&W_s[j * 128 + n0];
            const float4 w1 = *(const float4*)&W_s[j * 128 + n0 + 4];
            const float um4[4] = { um.x, um.y, um.z, um.w };
            const float wn[8] = { w0.x, w0.y, w0.z, w0.w, w1.x, w1.y, w1.z, w1.w };
#pragma unroll
            for (int mi = 0; mi < 4; ++mi)
#pragma unroll
                for (int ni = 0; ni < 8; ++ni)
                    acc[mi][ni] = fmaf(um4[mi], wn[ni], acc[mi][ni]);
        }
    }

    // epilogue: +bias, SiLU, float4 stores
    int pr = m0 >> 3, pc = m0 & 7;
    int oh = oh0 + pr;
    size_t base = ((size_t)b * OUP_) * (H_ * W_);
#pragma unroll
    for (int ni = 0; ni < 8; ++ni) {
        int oup = n0 + ni;
        float bo = bias_s[oup];
        float4 o4;
        float z0 = acc[0][ni] + bo; o4.x = z0 * sigmf(z0);
        float z1 = acc[1][ni] + bo; o4.y = z1 * sigmf(z1);
        float z2 = acc[2][ni] + bo; o4.z = z2 * sigmf(z2);
        float z3 = acc[3][ni] + bo; o4.w = z3 * sigmf(z3);
        *(float4*)&out[base + (size_t)oup * (H_ * W_) + (size_t)oh * W_ + ow0 + pc] = o4;
    }
}

extern "C" void kernel_launch(void* const* d_in, const int* in_sizes, int n_in,
                              void* d_out, int out_size, void* d_ws, size_t ws_size,
                              hipStream_t stream)
{
    const float* x      = (const float*)d_in[0];
    const float* gen_w  = (const float*)d_in[1];
    const float* gg     = (const float*)d_in[2];
    const float* gb     = (const float*)d_in[3];
    const float* gm     = (const float*)d_in[4];
    const float* gv     = (const float*)d_in[5];
    const float* gnw    = (const float*)d_in[6];
    const float* gnb    = (const float*)d_in[7];
    const float* cwt    = (const float*)d_in[8];
    const float* cbs    = (const float*)d_in[9];
    const float* swt    = (const float*)d_in[10];
    const float* sbs    = (const float*)d_in[11];
    const float* wadd   = (const float*)d_in[12];
    const float* conv_w = (const float*)d_in[13];
    const float* cg2    = (const float*)d_in[14];
    const float* cb2    = (const float*)d_in[15];
    const float* cm2    = (const float*)d_in[16];
    const float* cv2    = (const float*)d_in[17];
    float* ws  = (float*)d_ws;
    float* out = (float*)d_out;

    k_fold<<<311, 256, 0, stream>>>(gen_w, gg, gb, gm, gv, conv_w, cg2, cb2, cm2, cv2, ws);
    k_stats<<<512, 256, 0, stream>>>(x, ws, cwt, cbs, swt, sbs, gnw, gnb, wadd,
                                     (float4*)(ws + WS_GATE));
    k_main<<<2048, 256, 0, stream>>>(x, ws, out);
}

// Round 2
// 273.921 us; speedup vs baseline: 1.9628x; 1.9628x over previous
//
#include <hip/hip_runtime.h>
#include <math.h>

// SIFA fused, MFMA version.
// z[b,o,oh,ow] = sum_{c,j} conv_w[o,c,j] * gate(y[b,c*9+j,oh,ow]), per block a
// 128oup x 128px GEMM with K = 64 chans * 16 (9 real + 7 zero-pad) done in
// f16 MFMA 16x16x32. u values are recomputed on the fly (dwconv+BN+ReLU+gates);
// per-(b,c) stats come from k_stats/k_gate.

#define EPSF 1e-5f
typedef _Float16 v8h __attribute__((ext_vector_type(8)));
typedef float v4f __attribute__((ext_vector_type(4)));

static constexpr int C_ = 64, HW_ = 16384, W_ = 128;

// ws float offsets
static constexpr int WS_WFOLD = 0;      // 5184: [c][j][k] folded depthwise weights
static constexpr int WS_SHIFT = 5184;   // 576
static constexpr int WS_BIAS  = 5760;   // 128
static constexpr int WS_GATE  = 5888;   // 512*4 {wa*cgate, 1-wa, a_sp, b_sp}
static constexpr int WS_PART  = 7936;   // 2048*2 partial sums
static constexpr int WS_WH    = 12032;  // 131072 f16: Wh[oup][c*16+j] (j<9), else 0

__device__ __forceinline__ float sigmf(float v) { return 1.f / (1.f + __expf(-v)); }

__global__ __launch_bounds__(256) void k_fold(
    const float* __restrict__ gen_w,
    const float* __restrict__ gg, const float* __restrict__ gb,
    const float* __restrict__ gm, const float* __restrict__ gv,
    const float* __restrict__ conv_w,
    const float* __restrict__ cg, const float* __restrict__ cb,
    const float* __restrict__ cm, const float* __restrict__ cv,
    float* __restrict__ ws)
{
    int idx = blockIdx.x * 256 + threadIdx.x;
    _Float16* Whp = (_Float16*)(ws + WS_WH);
    if (idx < 131072) {
        int oup = idx >> 10, kk = idx & 1023, c = kk >> 4, j = kk & 15;
        float s = cg[oup] * rsqrtf(cv[oup] + EPSF);
        float v = (j < 9) ? conv_w[(oup * C_ + c) * 9 + j] * s : 0.f;
        Whp[idx] = (_Float16)v;
    } else if (idx < 136256) {
        int i = idx - 131072; int ce = i / 9;
        float s = gg[ce] * rsqrtf(gv[ce] + EPSF);
        ws[WS_WFOLD + i] = gen_w[i] * s;
    } else if (idx < 136832) {
        int ce = idx - 136256;
        float s = gg[ce] * rsqrtf(gv[ce] + EPSF);
        ws[WS_SHIFT + ce] = gb[ce] - gm[ce] * s;
    } else if (idx < 136960) {
        int oup = idx - 136832;
        float s = cg[oup] * rsqrtf(cv[oup] + EPSF);
        ws[WS_BIAS + oup] = cb[oup] - cm[oup] * s;
    }
}

// 2048 blocks: (b, c, quarter). LDS-staged slab, partials to ws.
__global__ __launch_bounds__(256) void k_stats(
    const float* __restrict__ x, const float* __restrict__ ws,
    float* __restrict__ part)
{
    __shared__ float xs[34 * 132];
    __shared__ float r1[256], r2[256];
    int bid = blockIdx.x; int b = bid >> 8; int c = (bid >> 2) & 63; int q = bid & 3;
    int t = threadIdx.x;
    const float* xp = x + (size_t)(b * C_ + c) * HW_;
    for (int i = t; i < 4420; i += 256) {
        int r = i / 130, cc = i - r * 130;
        int yy = q * 32 + r - 1, xx = cc - 1;
        float v = 0.f;
        if (yy >= 0 && yy < 128 && xx >= 0 && xx < 128) v = xp[yy * 128 + xx];
        xs[r * 132 + cc] = v;
    }
    __syncthreads();
    const float* wf = ws + WS_WFOLD + c * 81;   // block-uniform -> scalar loads
    const float* sh = ws + WS_SHIFT + c * 9;
    float s1 = 0.f, s2 = 0.f;
    for (int i = 0; i < 16; ++i) {
        int id = i * 256 + t; int row = id >> 7, col = id & 127;
        float nb[9];
#pragma unroll
        for (int dy = 0; dy < 3; ++dy)
#pragma unroll
            for (int dx = 0; dx < 3; ++dx) nb[dy * 3 + dx] = xs[(row + dy) * 132 + col + dx];
#pragma unroll
        for (int j = 0; j < 9; ++j) {
            float v = sh[j];
#pragma unroll
            for (int k = 0; k < 9; ++k) v = fmaf(wf[j * 9 + k], nb[k], v);
            v = fmaxf(v, 0.f);
            s1 += v; s2 = fmaf(v, v, s2);
        }
    }
    r1[t] = s1; r2[t] = s2;
    __syncthreads();
    for (int s = 128; s > 0; s >>= 1) {
        if (t < s) { r1[t] += r1[t + s]; r2[t] += r2[t + s]; }
        __syncthreads();
    }
    if (t == 0) { part[bid * 2] = r1[0]; part[bid * 2 + 1] = r2[0]; }
}

__global__ __launch_bounds__(256) void k_gate(
    const float* __restrict__ part,
    const float* __restrict__ cwt, const float* __restrict__ cbs,
    const float* __restrict__ swt, const float* __restrict__ sbs,
    const float* __restrict__ gnw, const float* __restrict__ gnb,
    const float* __restrict__ wadd, float4* __restrict__ gate)
{
    int i = blockIdx.x * 256 + threadIdx.x;
    if (i >= 512) return;
    int b = i >> 6, c = i & 63;
    float s1 = 0.f, s2 = 0.f;
    for (int q = 0; q < 4; ++q) {
        int pi = (b * 256 + c * 4 + q) * 2;
        s1 += part[pi]; s2 += part[pi + 1];
    }
    const float N = 9.f * 16384.f;
    float mean = s1 / N;
    float var = s2 / N - mean * mean;
    float inv = rsqrtf(var + EPSF);
    int cgi = c & 7;
    float wa = wadd[0];
    float cgt = sigmf(cwt[cgi] * mean + cbs[cgi]);
    float4 o;
    o.x = wa * cgt;
    o.y = 1.f - wa;
    o.z = swt[cgi] * gnw[cgi] * inv;
    o.w = swt[cgi] * (gnb[cgi] - mean * inv * gnw[cgi]) + sbs[cgi];
    gate[i] = o;
}

// 1024 blocks: (b, 16x8 pixel tile). 128oup x 128px f32 acc via f16 MFMA.
__global__ __launch_bounds__(256) void k_main(
    const float* __restrict__ x, const float* __restrict__ ws,
    float* __restrict__ out)
{
    __shared__ _Float16 W_s[128 * 64];  // row=oup, 64 f16 (one iter's K-chunk), XOR-swizzled
    __shared__ _Float16 u_s[128 * 64];  // row=pixel
    __shared__ float xs4[4 * 200];      // 4 chans x (10 rows x stride 20)
    __shared__ float bias_s[128];

    int t = threadIdx.x;
    int bid = blockIdx.x;
    int b = bid >> 7, tile = bid & 127;
    int oh0 = (tile >> 3) << 3, ow0 = (tile & 7) << 4;
    if (t < 128) bias_s[t] = ws[WS_BIAS + t];

    const float* xb = x + (size_t)b * C_ * HW_;
    const _Float16* Wh = (const _Float16*)(ws + WS_WH);

    int lane = t & 63, w = t >> 6, quad = lane >> 4, l15 = lane & 15;
    int p = t & 127, cc0 = t >> 7;
    int py = p >> 4, px = p & 15;

    v4f acc[4][4];
#pragma unroll
    for (int a = 0; a < 4; ++a)
#pragma unroll
        for (int bb = 0; bb < 4; ++bb) acc[a][bb] = (v4f)0.f;

    for (int it = 0; it < 16; ++it) {
        int c0 = it * 4;
        __syncthreads();
        // ---- stage x halo for 4 channels (10 x 18 each)
        for (int i = t; i < 720; i += 256) {
            int ch = i / 180; int rem = i - ch * 180; int r = rem / 18; int cl = rem - r * 18;
            int yy = oh0 + r - 1, xx = ow0 + cl - 1;
            float v = 0.f;
            if (yy >= 0 && yy < 128 && xx >= 0 && xx < 128) v = xb[(c0 + ch) * HW_ + yy * 128 + xx];
            xs4[ch * 200 + r * 20 + cl] = v;
        }
        // ---- stage W chunk (128 oups x 64 f16) with XOR swizzle
#pragma unroll
        for (int i = 0; i < 4; ++i) {
            int id = t + i * 256; int oup = id >> 3, kb = id & 7;
            float4 v = *(const float4*)(Wh + oup * 1024 + it * 64 + kb * 8);
            *(float4*)&W_s[oup * 64 + ((kb ^ (oup & 7)) << 3)] = v;
        }
        __syncthreads();
        // ---- u-phase: 2 (pixel, channel) items per thread
#pragma unroll
        for (int uit = 0; uit < 2; ++uit) {
            int cc = cc0 + uit * 2;
            int cs = __builtin_amdgcn_readfirstlane(c0 + cc);
            const float* wfp = ws + WS_WFOLD + cs * 81;    // scalar (s_load) path
            const float* shp = ws + WS_SHIFT + cs * 9;
            const float* gp  = ws + WS_GATE + (((b << 6) + cs) << 2);
            float gx = gp[0], gy = gp[1], gz = gp[2], gw = gp[3];
            float nb[9];
#pragma unroll
            for (int dy = 0; dy < 3; ++dy)
#pragma unroll
                for (int dx = 0; dx < 3; ++dx)
                    nb[dy * 3 + dx] = xs4[cc * 200 + (py + dy) * 20 + px + dx];
            float uv[9];
#pragma unroll
            for (int j = 0; j < 9; ++j) uv[j] = shp[j];
#pragma unroll
            for (int k = 0; k < 9; ++k) {
                float xv = nb[k];
#pragma unroll
                for (int j = 0; j < 9; ++j) uv[j] = fmaf(wfp[j * 9 + k], xv, uv[j]);
            }
            union { _Float16 h[16]; float4 q[2]; } pk;
#pragma unroll
            for (int j = 0; j < 9; ++j) {
                float v = fmaxf(uv[j], 0.f);
                float g2 = fmaf(gy, sigmf(fmaf(gz, v, gw)), gx);
                pk.h[j] = (_Float16)(v * g2);
            }
#pragma unroll
            for (int j = 9; j < 16; ++j) pk.h[j] = (_Float16)0.f;
            int b0 = cc * 2;
            *(float4*)&u_s[p * 64 + ((b0 ^ (p & 7)) << 3)] = pk.q[0];
            *(float4*)&u_s[p * 64 + (((b0 + 1) ^ (p & 7)) << 3)] = pk.q[1];
        }
        __syncthreads();
        // ---- MFMA: wave w owns oups [(w&1)*64, +64) x pixels [(w>>1)*64, +64)
#pragma unroll
        for (int ks = 0; ks < 2; ++ks) {
            int kb = ks * 4 + quad;
            v8h A[4], Bf[4];
#pragma unroll
            for (int a = 0; a < 4; ++a) {
                int row = ((w & 1) << 6) + (a << 4) + l15;
                A[a] = *(const v8h*)&W_s[row * 64 + ((kb ^ (row & 7)) << 3)];
            }
#pragma unroll
            for (int bb = 0; bb < 4; ++bb) {
                int row = ((w >> 1) << 6) + (bb << 4) + l15;
                Bf[bb] = *(const v8h*)&u_s[row * 64 + ((kb ^ (row & 7)) << 3)];
            }
#pragma unroll
            for (int a = 0; a < 4; ++a)
#pragma unroll
                for (int bb = 0; bb < 4; ++bb)
                    acc[a][bb] = __builtin_amdgcn_mfma_f32_16x16x32_f16(A[a], Bf[bb], acc[a][bb], 0, 0, 0);
        }
    }

    // ---- epilogue: bias + SiLU; C/D layout col=lane&15(px), row=quad*4+reg(oup)
    size_t ob = (size_t)b * 128 * HW_;
#pragma unroll
    for (int a = 0; a < 4; ++a) {
#pragma unroll
        for (int r = 0; r < 4; ++r) {
            int oup = ((w & 1) << 6) + (a << 4) + (quad << 2) + r;
            float bo = bias_s[oup];
#pragma unroll
            for (int bb = 0; bb < 4; ++bb) {
                int p2 = ((w >> 1) << 6) + (bb << 4) + l15;
                int py2 = p2 >> 4, px2 = p2 & 15;
                float z = acc[a][bb][r] + bo;
                out[ob + (size_t)oup * HW_ + (oh0 + py2) * W_ + ow0 + px2] = z * sigmf(z);
            }
        }
    }
}

extern "C" void kernel_launch(void* const* d_in, const int* in_sizes, int n_in,
                              void* d_out, int out_size, void* d_ws, size_t ws_size,
                              hipStream_t stream)
{
    const float* x      = (const float*)d_in[0];
    const float* gen_w  = (const float*)d_in[1];
    const float* gg     = (const float*)d_in[2];
    const float* gb     = (const float*)d_in[3];
    const float* gm     = (const float*)d_in[4];
    const float* gv     = (const float*)d_in[5];
    const float* gnw    = (const float*)d_in[6];
    const float* gnb    = (const float*)d_in[7];
    const float* cwt    = (const float*)d_in[8];
    const float* cbs    = (const float*)d_in[9];
    const float* swt    = (const float*)d_in[10];
    const float* sbs    = (const float*)d_in[11];
    const float* wadd   = (const float*)d_in[12];
    const float* conv_w = (const float*)d_in[13];
    const float* cg2    = (const float*)d_in[14];
    const float* cb2    = (const float*)d_in[15];
    const float* cm2    = (const float*)d_in[16];
    const float* cv2    = (const float*)d_in[17];
    float* ws  = (float*)d_ws;
    float* out = (float*)d_out;

    k_fold<<<535, 256, 0, stream>>>(gen_w, gg, gb, gm, gv, conv_w, cg2, cb2, cm2, cv2, ws);
    k_stats<<<2048, 256, 0, stream>>>(x, ws, ws + WS_PART);
    k_gate<<<2, 256, 0, stream>>>(ws + WS_PART, cwt, cbs, swt, sbs, gnw, gnb, wadd,
                                  (float4*)(ws + WS_GATE));
    k_main<<<1024, 256, 0, stream>>>(x, ws, out);
}